// Round 1
// baseline (1482.698 us; speedup 1.0000x reference)
//
#include <hip/hip_runtime.h>
#include <math.h>

#define Bn 4
#define Cn 256
#define Hn 64
#define Wn 64
#define On 256
#define HWn 4096
#define Pn 16384   // B*H*W

// ---------------------------------------------------------------------------
// Tiled 2D transpose per batch: in[b][r][c] -> out[b][c][r]
// grid: (Cc/32, R/32, B), block: (32,8)
__global__ void k_transpose(const float* __restrict__ in, float* __restrict__ out,
                            int R, int Cc) {
  __shared__ float tile[32][33];
  int b = blockIdx.z;
  int c0 = blockIdx.x * 32, r0 = blockIdx.y * 32;
  const float* ib = in + (size_t)b * R * Cc;
  float* ob = out + (size_t)b * R * Cc;
  int tx = threadIdx.x, ty = threadIdx.y;
#pragma unroll
  for (int i = 0; i < 32; i += 8)
    tile[ty + i][tx] = ib[(size_t)(r0 + ty + i) * Cc + (c0 + tx)];
  __syncthreads();
#pragma unroll
  for (int i = 0; i < 32; i += 8)
    ob[(size_t)(c0 + ty + i) * R + (r0 + tx)] = tile[tx][ty + i];
}

// ---------------------------------------------------------------------------
// Weight transposes: w[o][ci][3][3] -> wt[k][ci][o]  (k = ky*3+kx)
__global__ void k_wt_main(const float* __restrict__ w, float* __restrict__ wt) {
  int idx = blockIdx.x * 256 + threadIdx.x;   // 9*256*256
  int o = idx & 255;
  int ci = (idx >> 8) & 255;
  int k = idx >> 16;
  wt[idx] = w[((size_t)o * 256 + ci) * 9 + k];
}

// w_off[oc(27)][ci][3][3] -> wofft[k][ci][oc(32 padded)]
__global__ void k_wt_off(const float* __restrict__ w, float* __restrict__ wt) {
  int idx = blockIdx.x * 256 + threadIdx.x;   // 9*256*32
  int oc = idx & 31;
  int ci = (idx >> 5) & 255;
  int k = idx >> 13;
  wt[idx] = (oc < 27) ? w[((size_t)oc * 256 + ci) * 9 + k] : 0.f;
}

// ---------------------------------------------------------------------------
// Offset conv as tiled GEMM: om[p][0..31] = sum_{t,ci} xh[shift(p,t)][ci]*wofft[t][ci][oc] + b_off
// grid: Pn/64, block 256. Mt=64, Nt=32, BK=16.
__global__ __launch_bounds__(256) void k_gemm_off(const float* __restrict__ xh,
                                                  const float* __restrict__ wofft,
                                                  const float* __restrict__ boff,
                                                  float* __restrict__ om) {
  __shared__ float As[16][64];
  __shared__ float Bs[16][32];
  int p0 = blockIdx.x * 64;
  int tid = threadIdx.x;

  // A-gather role
  int lp = tid & 63;       // pixel in tile
  int lci = tid >> 6;      // 0..3
  int p = p0 + lp;
  int bimg = p >> 12;
  int yx = p & 4095;
  int y = yx >> 6, x = yx & 63;

  // compute role: 2 rows x 4 cols
  int tx = tid & 7;        // cols 4*tx (0..31)
  int ty = tid >> 3;       // rows 2*ty (0..63)

  // B-load role
  int boc = tid & 31;
  int bkg = tid >> 5;      // 0..7

  float acc[2][4] = {};

  for (int t = 0; t < 9; ++t) {
    int sy = y + t / 3 - 1;
    int sx = x + t % 3 - 1;
    bool valid = (sy >= 0) & (sy < Hn) & (sx >= 0) & (sx < Wn);
    const float* src = xh + (size_t)(((bimg * Hn + (valid ? sy : 0)) * Wn) + (valid ? sx : 0)) * Cn;

    for (int c0 = 0; c0 < Cn; c0 += 16) {
      float4 v = valid ? *(const float4*)(src + c0 + 4 * lci) : make_float4(0.f, 0.f, 0.f, 0.f);
      As[4 * lci + 0][lp] = v.x;
      As[4 * lci + 1][lp] = v.y;
      As[4 * lci + 2][lp] = v.z;
      As[4 * lci + 3][lp] = v.w;
      {
        const float* wsrc = wofft + (size_t)(t * 256 + c0) * 32;
        Bs[bkg][boc]     = wsrc[(size_t)bkg * 32 + boc];
        Bs[bkg + 8][boc] = wsrc[(size_t)(bkg + 8) * 32 + boc];
      }
      __syncthreads();
#pragma unroll
      for (int kk = 0; kk < 16; ++kk) {
        float2 a2 = *(const float2*)&As[kk][2 * ty];
        float4 b4 = *(const float4*)&Bs[kk][4 * tx];
        acc[0][0] += a2.x * b4.x; acc[0][1] += a2.x * b4.y;
        acc[0][2] += a2.x * b4.z; acc[0][3] += a2.x * b4.w;
        acc[1][0] += a2.y * b4.x; acc[1][1] += a2.y * b4.y;
        acc[1][2] += a2.y * b4.z; acc[1][3] += a2.y * b4.w;
      }
      __syncthreads();
    }
  }
#pragma unroll
  for (int i = 0; i < 2; ++i) {
    int pp = p0 + 2 * ty + i;
#pragma unroll
    for (int j = 0; j < 4; ++j) {
      int oc = 4 * tx + j;
      float bias = (oc < 27) ? boff[oc] : 0.f;
      om[(size_t)pp * 32 + oc] = acc[i][j] + bias;
    }
  }
}

// ---------------------------------------------------------------------------
// Coords: om[p][32] -> samp[p][9] = {int o00,o01,o10,o11; float w00,w01,w10,w11}
// bilinear weights pre-multiplied by sigmoid mask, zeroed for OOB corners;
// offsets clamped (safe to load, weight 0).
__global__ void k_coords(const float* __restrict__ om, float* __restrict__ samp) {
  int idx = blockIdx.x * 256 + threadIdx.x;   // Pn*9
  int k = idx % 9;
  int p = idx / 9;
  int bimg = p >> 12;
  int yx = p & 4095;
  int y = yx >> 6, x = yx & 63;

  const float* o = om + (size_t)p * 32;
  float dy = o[2 * k];
  float dx = o[2 * k + 1];
  float m = 1.f / (1.f + expf(-o[18 + k]));

  float ys = (float)(y + k / 3 - 1) + dy;
  float xs = (float)(x + k % 3 - 1) + dx;
  float y0f = floorf(ys), x0f = floorf(xs);
  float wy = ys - y0f, wx = xs - x0f;
  int y0 = (int)y0f, x0 = (int)x0f;
  int y1 = y0 + 1, x1 = x0 + 1;

  bool vy0 = (y0 >= 0) & (y0 < Hn);
  bool vy1 = (y1 >= 0) & (y1 < Hn);
  bool vx0 = (x0 >= 0) & (x0 < Wn);
  bool vx1 = (x1 >= 0) & (x1 < Wn);
  int y0c = min(max(y0, 0), Hn - 1), y1c = min(max(y1, 0), Hn - 1);
  int x0c = min(max(x0, 0), Wn - 1), x1c = min(max(x1, 0), Wn - 1);

  int base = bimg * HWn;
  int o00 = (base + y0c * Wn + x0c) * Cn;
  int o01 = (base + y0c * Wn + x1c) * Cn;
  int o10 = (base + y1c * Wn + x0c) * Cn;
  int o11 = (base + y1c * Wn + x1c) * Cn;

  float w00 = (vy0 && vx0) ? m * (1.f - wy) * (1.f - wx) : 0.f;
  float w01 = (vy0 && vx1) ? m * (1.f - wy) * wx : 0.f;
  float w10 = (vy1 && vx0) ? m * wy * (1.f - wx) : 0.f;
  float w11 = (vy1 && vx1) ? m * wy * wx : 0.f;

  float* s = samp + (size_t)idx * 8;
  ((int*)s)[0] = o00; ((int*)s)[1] = o01; ((int*)s)[2] = o10; ((int*)s)[3] = o11;
  s[4] = w00; s[5] = w01; s[6] = w10; s[7] = w11;
}

// ---------------------------------------------------------------------------
// Main deformable GEMM: out[p][o] = relu( sum_{k,ci} gather(p,k,ci)*wt[k][ci][o] + b[o] )
// grid: (Pn/64, On/128), block 256. Mt=64, Nt=128, BK=16, micro 4x8.
__global__ __launch_bounds__(256) void k_gemm_main(const float* __restrict__ xh,
                                                   const float* __restrict__ samp,
                                                   const float* __restrict__ wt,
                                                   const float* __restrict__ bias,
                                                   float* __restrict__ out) {
  __shared__ float As[16][64];
  __shared__ float Bs[16][128];
  __shared__ int4 So[64];
  __shared__ float4 Sw[64];

  int p0 = blockIdx.x * 64;
  int o0 = blockIdx.y * 128;
  int tid = threadIdx.x;

  int lp = tid & 63;   // A-gather pixel
  int lci = tid >> 6;  // 0..3

  int tx = tid & 15;   // cols 8*tx
  int ty = tid >> 4;   // rows 4*ty

  int boc4 = (tid & 31) * 4;  // B-load col (float4)
  int bkk = tid >> 5;         // 0..7

  float acc[4][8] = {};

  for (int k = 0; k < 9; ++k) {
    __syncthreads();
    if (tid < 64) {
      const float* s = samp + (size_t)((p0 + tid) * 9 + k) * 8;
      So[tid] = *(const int4*)s;
      Sw[tid] = *(const float4*)(s + 4);
    }
    __syncthreads();
    int4 ofs = So[lp];
    float4 wv = Sw[lp];

    for (int c0 = 0; c0 < Cn; c0 += 16) {
      int cc = c0 + 4 * lci;
      float4 v00 = *(const float4*)(xh + ofs.x + cc);
      float4 v01 = *(const float4*)(xh + ofs.y + cc);
      float4 v10 = *(const float4*)(xh + ofs.z + cc);
      float4 v11 = *(const float4*)(xh + ofs.w + cc);
      float4 v;
      v.x = wv.x * v00.x + wv.y * v01.x + wv.z * v10.x + wv.w * v11.x;
      v.y = wv.x * v00.y + wv.y * v01.y + wv.z * v10.y + wv.w * v11.y;
      v.z = wv.x * v00.z + wv.y * v01.z + wv.z * v10.z + wv.w * v11.z;
      v.w = wv.x * v00.w + wv.y * v01.w + wv.z * v10.w + wv.w * v11.w;
      As[4 * lci + 0][lp] = v.x;
      As[4 * lci + 1][lp] = v.y;
      As[4 * lci + 2][lp] = v.z;
      As[4 * lci + 3][lp] = v.w;
      {
        const float* w0 = wt + ((size_t)(k * 256 + c0 + bkk) * 256) + o0;
        const float* w1 = wt + ((size_t)(k * 256 + c0 + bkk + 8) * 256) + o0;
        *(float4*)&Bs[bkk][boc4]     = *(const float4*)(w0 + boc4);
        *(float4*)&Bs[bkk + 8][boc4] = *(const float4*)(w1 + boc4);
      }
      __syncthreads();
#pragma unroll
      for (int kk = 0; kk < 16; ++kk) {
        float4 a4 = *(const float4*)&As[kk][4 * ty];
        float4 b0 = *(const float4*)&Bs[kk][8 * tx];
        float4 b1 = *(const float4*)&Bs[kk][8 * tx + 4];
        acc[0][0] += a4.x * b0.x; acc[0][1] += a4.x * b0.y; acc[0][2] += a4.x * b0.z; acc[0][3] += a4.x * b0.w;
        acc[0][4] += a4.x * b1.x; acc[0][5] += a4.x * b1.y; acc[0][6] += a4.x * b1.z; acc[0][7] += a4.x * b1.w;
        acc[1][0] += a4.y * b0.x; acc[1][1] += a4.y * b0.y; acc[1][2] += a4.y * b0.z; acc[1][3] += a4.y * b0.w;
        acc[1][4] += a4.y * b1.x; acc[1][5] += a4.y * b1.y; acc[1][6] += a4.y * b1.z; acc[1][7] += a4.y * b1.w;
        acc[2][0] += a4.z * b0.x; acc[2][1] += a4.z * b0.y; acc[2][2] += a4.z * b0.z; acc[2][3] += a4.z * b0.w;
        acc[2][4] += a4.z * b1.x; acc[2][5] += a4.z * b1.y; acc[2][6] += a4.z * b1.z; acc[2][7] += a4.z * b1.w;
        acc[3][0] += a4.w * b0.x; acc[3][1] += a4.w * b0.y; acc[3][2] += a4.w * b0.z; acc[3][3] += a4.w * b0.w;
        acc[3][4] += a4.w * b1.x; acc[3][5] += a4.w * b1.y; acc[3][6] += a4.w * b1.z; acc[3][7] += a4.w * b1.w;
      }
      __syncthreads();
    }
  }

  // epilogue: bias + relu, NHWC write
#pragma unroll
  for (int i = 0; i < 4; ++i) {
    int pp = p0 + 4 * ty + i;
    float* orow = out + (size_t)pp * On + o0 + 8 * tx;
    float4 r0, r1;
    r0.x = fmaxf(acc[i][0] + bias[o0 + 8 * tx + 0], 0.f);
    r0.y = fmaxf(acc[i][1] + bias[o0 + 8 * tx + 1], 0.f);
    r0.z = fmaxf(acc[i][2] + bias[o0 + 8 * tx + 2], 0.f);
    r0.w = fmaxf(acc[i][3] + bias[o0 + 8 * tx + 3], 0.f);
    r1.x = fmaxf(acc[i][4] + bias[o0 + 8 * tx + 4], 0.f);
    r1.y = fmaxf(acc[i][5] + bias[o0 + 8 * tx + 5], 0.f);
    r1.z = fmaxf(acc[i][6] + bias[o0 + 8 * tx + 6], 0.f);
    r1.w = fmaxf(acc[i][7] + bias[o0 + 8 * tx + 7], 0.f);
    *(float4*)(orow) = r0;
    *(float4*)(orow + 4) = r1;
  }
}

// ---------------------------------------------------------------------------
extern "C" void kernel_launch(void* const* d_in, const int* in_sizes, int n_in,
                              void* d_out, int out_size, void* d_ws, size_t ws_size,
                              hipStream_t stream) {
  (void)in_sizes; (void)n_in; (void)out_size; (void)ws_size;
  const float* x = (const float*)d_in[0];
  float* ws = (float*)d_ws;

  float* act0  = ws;                               // Pn*Cn
  float* act1  = act0 + (size_t)Pn * Cn;           // Pn*Cn
  float* om    = act1 + (size_t)Pn * Cn;           // Pn*32
  float* samp  = om + (size_t)Pn * 32;             // Pn*9*8
  float* wt    = samp + (size_t)Pn * 9 * 8;        // 9*256*256
  float* wofft = wt + (size_t)9 * 256 * 256;       // 9*256*32

  dim3 tb(32, 8);
  // x NCHW -> act0 NHWC: rows=C(256), cols=HW(4096)
  k_transpose<<<dim3(HWn / 32, Cn / 32, Bn), tb, 0, stream>>>(x, act0, Cn, HWn);

  float* cur = act0;
  float* nxt = act1;
  for (int l = 0; l < 3; ++l) {
    const float* w_off = (const float*)d_in[1 + l * 4];
    const float* b_off = (const float*)d_in[2 + l * 4];
    const float* w     = (const float*)d_in[3 + l * 4];
    const float* b     = (const float*)d_in[4 + l * 4];

    k_wt_off<<<(9 * 256 * 32) / 256, 256, 0, stream>>>(w_off, wofft);
    k_wt_main<<<(9 * 256 * 256) / 256, 256, 0, stream>>>(w, wt);
    k_gemm_off<<<Pn / 64, 256, 0, stream>>>(cur, wofft, b_off, om);
    k_coords<<<(Pn * 9) / 256, 256, 0, stream>>>(om, samp);
    k_gemm_main<<<dim3(Pn / 64, On / 128), 256, 0, stream>>>(cur, samp, wt, b, nxt);

    float* t = cur; cur = nxt; nxt = t;
  }
  // cur NHWC -> d_out NCHW: rows=HW(4096), cols=O(256)
  k_transpose<<<dim3(On / 32, HWn / 32, Bn), tb, 0, stream>>>(cur, (float*)d_out, HWn, On);
}

// Round 2
// 751.002 us; speedup vs baseline: 1.9743x; 1.9743x over previous
//
#include <hip/hip_runtime.h>
#include <math.h>

#define Bn 4
#define Cn 256
#define Hn 64
#define Wn 64
#define On 256
#define HWn 4096
#define Pn 16384   // B*H*W
#define Kc 2304    // 9*256

typedef _Float16 half8 __attribute__((ext_vector_type(8)));
typedef _Float16 half4v __attribute__((ext_vector_type(4)));
typedef float floatx4 __attribute__((ext_vector_type(4)));

// ---------------------------------------------------------------------------
// fp32 NCHW -> f16 NHWC transpose (per batch). grid (HWn/32, Cn/32, B), block (32,8)
__global__ void k_transpose_f2h(const float* __restrict__ in, _Float16* __restrict__ out,
                                int R, int Cc) {
  __shared__ float tile[32][33];
  int b = blockIdx.z;
  int c0 = blockIdx.x * 32, r0 = blockIdx.y * 32;
  const float* ib = in + (size_t)b * R * Cc;
  _Float16* ob = out + (size_t)b * R * Cc;
  int tx = threadIdx.x, ty = threadIdx.y;
#pragma unroll
  for (int i = 0; i < 32; i += 8)
    tile[ty + i][tx] = ib[(size_t)(r0 + ty + i) * Cc + (c0 + tx)];
  __syncthreads();
#pragma unroll
  for (int i = 0; i < 32; i += 8)
    ob[(size_t)(c0 + ty + i) * R + (r0 + tx)] = (_Float16)tile[tx][ty + i];
}

// fp32 NHWC -> fp32 NCHW (final output)
__global__ void k_transpose(const float* __restrict__ in, float* __restrict__ out,
                            int R, int Cc) {
  __shared__ float tile[32][33];
  int b = blockIdx.z;
  int c0 = blockIdx.x * 32, r0 = blockIdx.y * 32;
  const float* ib = in + (size_t)b * R * Cc;
  float* ob = out + (size_t)b * R * Cc;
  int tx = threadIdx.x, ty = threadIdx.y;
#pragma unroll
  for (int i = 0; i < 32; i += 8)
    tile[ty + i][tx] = ib[(size_t)(r0 + ty + i) * Cc + (c0 + tx)];
  __syncthreads();
#pragma unroll
  for (int i = 0; i < 32; i += 8)
    ob[(size_t)(c0 + ty + i) * R + (r0 + tx)] = tile[tx][ty + i];
}

// ---------------------------------------------------------------------------
// Main-conv weights: w[o][ci][3][3] -> wth[o][t*256+ci] (f16, K contiguous per o-row)
__global__ void k_wt_h(const float* __restrict__ w, _Float16* __restrict__ wth) {
  int o = blockIdx.x;
  int ci = threadIdx.x;
  const float* src = w + ((size_t)o * 256 + ci) * 9;
#pragma unroll
  for (int t = 0; t < 9; ++t)
    wth[(size_t)o * Kc + t * 256 + ci] = (_Float16)src[t];
}

// Offset-conv weights: w_off[oc(27)][ci][3][3] -> wofft[t][ci][oc(32 padded)] fp32
__global__ void k_wt_off(const float* __restrict__ w, float* __restrict__ wt) {
  int idx = blockIdx.x * 256 + threadIdx.x;   // 9*256*32
  int oc = idx & 31;
  int ci = (idx >> 5) & 255;
  int t = idx >> 13;
  wt[idx] = (oc < 27) ? w[((size_t)oc * 256 + ci) * 9 + t] : 0.f;
}

// ---------------------------------------------------------------------------
// Offset conv (fp32 accumulate, f16 activations in): om[p][0..31]
// grid Pn/64, block 256. Mt=64, Nt=32, BK=16.
__global__ __launch_bounds__(256) void k_gemm_off(const _Float16* __restrict__ xh,
                                                  const float* __restrict__ wofft,
                                                  const float* __restrict__ boff,
                                                  float* __restrict__ om) {
  __shared__ float As[16][64];
  __shared__ float Bs[16][32];
  int p0 = blockIdx.x * 64;
  int tid = threadIdx.x;

  int lp = tid & 63;
  int lci = tid >> 6;      // 0..3
  int p = p0 + lp;
  int bimg = p >> 12;
  int yx = p & 4095;
  int y = yx >> 6, x = yx & 63;

  int tx = tid & 7;
  int ty = tid >> 3;

  int boc = tid & 31;
  int bkg = tid >> 5;

  float acc[2][4] = {};

  for (int t = 0; t < 9; ++t) {
    int sy = y + t / 3 - 1;
    int sx = x + t % 3 - 1;
    bool valid = (sy >= 0) & (sy < Hn) & (sx >= 0) & (sx < Wn);
    const _Float16* src = xh + (size_t)(((bimg * Hn + (valid ? sy : 0)) * Wn) + (valid ? sx : 0)) * Cn;

    for (int c0 = 0; c0 < Cn; c0 += 16) {
      half4v hv;
      if (valid) hv = *(const half4v*)(src + c0 + 4 * lci);
      else { hv[0] = (_Float16)0; hv[1] = (_Float16)0; hv[2] = (_Float16)0; hv[3] = (_Float16)0; }
      As[4 * lci + 0][lp] = (float)hv[0];
      As[4 * lci + 1][lp] = (float)hv[1];
      As[4 * lci + 2][lp] = (float)hv[2];
      As[4 * lci + 3][lp] = (float)hv[3];
      {
        const float* wsrc = wofft + (size_t)(t * 256 + c0) * 32;
        Bs[bkg][boc]     = wsrc[(size_t)bkg * 32 + boc];
        Bs[bkg + 8][boc] = wsrc[(size_t)(bkg + 8) * 32 + boc];
      }
      __syncthreads();
#pragma unroll
      for (int kk = 0; kk < 16; ++kk) {
        float2 a2 = *(const float2*)&As[kk][2 * ty];
        float4 b4 = *(const float4*)&Bs[kk][4 * tx];
        acc[0][0] += a2.x * b4.x; acc[0][1] += a2.x * b4.y;
        acc[0][2] += a2.x * b4.z; acc[0][3] += a2.x * b4.w;
        acc[1][0] += a2.y * b4.x; acc[1][1] += a2.y * b4.y;
        acc[1][2] += a2.y * b4.z; acc[1][3] += a2.y * b4.w;
      }
      __syncthreads();
    }
  }
#pragma unroll
  for (int i = 0; i < 2; ++i) {
    int pp = p0 + 2 * ty + i;
#pragma unroll
    for (int j = 0; j < 4; ++j) {
      int oc = 4 * tx + j;
      float bias = (oc < 27) ? boff[oc] : 0.f;
      om[(size_t)pp * 32 + oc] = acc[i][j] + bias;
    }
  }
}

// ---------------------------------------------------------------------------
// Coords: om[p][32] -> samp[p][9] = {int4 corner elem-offsets; float4 folded weights}
__global__ void k_coords(const float* __restrict__ om, float* __restrict__ samp) {
  int idx = blockIdx.x * 256 + threadIdx.x;   // Pn*9
  int k = idx % 9;
  int p = idx / 9;
  int bimg = p >> 12;
  int yx = p & 4095;
  int y = yx >> 6, x = yx & 63;

  const float* o = om + (size_t)p * 32;
  float dy = o[2 * k];
  float dx = o[2 * k + 1];
  float m = 1.f / (1.f + expf(-o[18 + k]));

  float ys = (float)(y + k / 3 - 1) + dy;
  float xs = (float)(x + k % 3 - 1) + dx;
  float y0f = floorf(ys), x0f = floorf(xs);
  float wy = ys - y0f, wx = xs - x0f;
  int y0 = (int)y0f, x0 = (int)x0f;
  int y1 = y0 + 1, x1 = x0 + 1;

  bool vy0 = (y0 >= 0) & (y0 < Hn);
  bool vy1 = (y1 >= 0) & (y1 < Hn);
  bool vx0 = (x0 >= 0) & (x0 < Wn);
  bool vx1 = (x1 >= 0) & (x1 < Wn);
  int y0c = min(max(y0, 0), Hn - 1), y1c = min(max(y1, 0), Hn - 1);
  int x0c = min(max(x0, 0), Wn - 1), x1c = min(max(x1, 0), Wn - 1);

  int base = bimg * HWn;
  int o00 = (base + y0c * Wn + x0c) * Cn;
  int o01 = (base + y0c * Wn + x1c) * Cn;
  int o10 = (base + y1c * Wn + x0c) * Cn;
  int o11 = (base + y1c * Wn + x1c) * Cn;

  float w00 = (vy0 && vx0) ? m * (1.f - wy) * (1.f - wx) : 0.f;
  float w01 = (vy0 && vx1) ? m * (1.f - wy) * wx : 0.f;
  float w10 = (vy1 && vx0) ? m * wy * (1.f - wx) : 0.f;
  float w11 = (vy1 && vx1) ? m * wy * wx : 0.f;

  float* s = samp + (size_t)idx * 8;
  ((int*)s)[0] = o00; ((int*)s)[1] = o01; ((int*)s)[2] = o10; ((int*)s)[3] = o11;
  s[4] = w00; s[5] = w01; s[6] = w10; s[7] = w11;
}

// ---------------------------------------------------------------------------
// Fused deformable-gather + f16 MFMA GEMM.
// out[p][n] = relu( sum_{t,ci} bilin(p,t,ci) * wth[n][t*256+ci] + bias[n] )
// Mt=32, Nt=256(=On), BK=64. grid Pn/32=512 blocks, block 256 (4 waves).
// Wave w: n in [w*64, w*64+64), frags 2(m) x 4(n) of 16x16x32.
// A staged in LDS (gathered once per block); B-frags loaded direct from global
// (wth L2-resident, [n][k] row-major so a lane's 8 k-elems are contiguous).
__global__ __launch_bounds__(256) void k_gemm_main(
    const _Float16* __restrict__ xh, const float* __restrict__ samp,
    const _Float16* __restrict__ wth, const float* __restrict__ bias,
    _Float16* __restrict__ outh, float* __restrict__ outf) {
  __shared__ __align__(16) _Float16 As[32][72];   // pad 64->72 halves: 2-way-max frag reads
  __shared__ int4 So[288];                         // samp offsets, 32 rows x 9 taps
  __shared__ float4 Sw[288];

  int p0 = blockIdx.x * 32;
  int tid = threadIdx.x;
  int lane = tid & 63;
  int wave = tid >> 6;
  int wn = wave * 64;
  int quad = lane >> 4;
  int col = lane & 15;

  // preload samp for rows p0..p0+31 (contiguous 288 x 32B)
  {
    const float* base = samp + (size_t)p0 * 9 * 8;
    for (int e = tid; e < 288; e += 256) {
      So[e] = *(const int4*)(base + (size_t)e * 8);
      Sw[e] = *(const float4*)(base + (size_t)e * 8 + 4);
    }
  }

  float bj[4];
#pragma unroll
  for (int j = 0; j < 4; ++j) bj[j] = bias[wn + j * 16 + col];

  floatx4 acc[2][4];
#pragma unroll
  for (int i = 0; i < 2; ++i)
#pragma unroll
    for (int j = 0; j < 4; ++j) acc[i][j] = (floatx4){0.f, 0.f, 0.f, 0.f};

  int ar = tid & 31;     // A-build row
  int aseg = tid >> 5;   // 0..7 -> 8-channel segment
  int aci = aseg * 8;

  __syncthreads();

  for (int t = 0; t < 9; ++t) {
    int4 ofs = So[ar * 9 + t];
    float4 wv4 = Sw[ar * 9 + t];
    _Float16 h00 = (_Float16)wv4.x;
    _Float16 h01 = (_Float16)wv4.y;
    _Float16 h10 = (_Float16)wv4.z;
    _Float16 h11 = (_Float16)wv4.w;

    for (int ci0 = 0; ci0 < 256; ci0 += 64) {
      int kg = t * 256 + ci0;

      // B-fragments straight from global (issue before A-build to overlap latency)
      half8 bfrag[2][4];
#pragma unroll
      for (int kq = 0; kq < 2; ++kq)
#pragma unroll
        for (int j = 0; j < 4; ++j) {
          int n = wn + j * 16 + col;
          bfrag[kq][j] = *(const half8*)(wth + (size_t)n * Kc + kg + kq * 32 + quad * 8);
        }

      // A build: gather 4 corners, bilinear in f16, write 8 halves to LDS
      {
        int ci = ci0 + aci;
        half8 c00 = *(const half8*)(xh + (size_t)ofs.x + ci);
        half8 c01 = *(const half8*)(xh + (size_t)ofs.y + ci);
        half8 c10 = *(const half8*)(xh + (size_t)ofs.z + ci);
        half8 c11 = *(const half8*)(xh + (size_t)ofs.w + ci);
        half8 r;
#pragma unroll
        for (int e = 0; e < 8; ++e)
          r[e] = c00[e] * h00 + c01[e] * h01 + c10[e] * h10 + c11[e] * h11;
        *(half8*)&As[ar][aci] = r;
      }
      __syncthreads();

      half8 afrag[2][2];
#pragma unroll
      for (int kq = 0; kq < 2; ++kq)
#pragma unroll
        for (int i = 0; i < 2; ++i)
          afrag[kq][i] = *(const half8*)&As[i * 16 + col][kq * 32 + quad * 8];

#pragma unroll
      for (int kq = 0; kq < 2; ++kq)
#pragma unroll
        for (int i = 0; i < 2; ++i)
#pragma unroll
          for (int j = 0; j < 4; ++j)
            acc[i][j] = __builtin_amdgcn_mfma_f32_16x16x32_f16(
                afrag[kq][i], bfrag[kq][j], acc[i][j], 0, 0, 0);
      __syncthreads();
    }
  }

  // epilogue: bias + relu; f16 activations (or fp32 for the last layer)
#pragma unroll
  for (int i = 0; i < 2; ++i)
#pragma unroll
    for (int j = 0; j < 4; ++j) {
      int n = wn + j * 16 + col;
#pragma unroll
      for (int r = 0; r < 4; ++r) {
        int p = p0 + i * 16 + quad * 4 + r;
        float v = fmaxf(acc[i][j][r] + bj[j], 0.f);
        if (outf) outf[(size_t)p * On + n] = v;
        else outh[(size_t)p * On + n] = (_Float16)v;
      }
    }
}

// ---------------------------------------------------------------------------
extern "C" void kernel_launch(void* const* d_in, const int* in_sizes, int n_in,
                              void* d_out, int out_size, void* d_ws, size_t ws_size,
                              hipStream_t stream) {
  (void)in_sizes; (void)n_in; (void)out_size; (void)ws_size;
  const float* x = (const float*)d_in[0];

  _Float16* act0h = (_Float16*)d_ws;                     // Pn*Cn f16
  _Float16* act1h = act0h + (size_t)Pn * Cn;             // Pn*Cn f16
  float* actf32   = (float*)(act1h + (size_t)Pn * Cn);   // Pn*On f32
  float* om       = actf32 + (size_t)Pn * On;            // Pn*32
  float* sampb    = om + (size_t)Pn * 32;                // Pn*9*8
  float* wofft    = sampb + (size_t)Pn * 9 * 8;          // 9*256*32
  _Float16* wth   = (_Float16*)(wofft + 9 * 256 * 32);   // 256*2304 f16

  dim3 tb(32, 8);
  k_transpose_f2h<<<dim3(HWn / 32, Cn / 32, Bn), tb, 0, stream>>>(x, act0h, Cn, HWn);

  _Float16* cur = act0h;
  _Float16* nxt = act1h;
  for (int l = 0; l < 3; ++l) {
    const float* w_off = (const float*)d_in[1 + l * 4];
    const float* b_off = (const float*)d_in[2 + l * 4];
    const float* w     = (const float*)d_in[3 + l * 4];
    const float* b     = (const float*)d_in[4 + l * 4];

    k_wt_off<<<(9 * 256 * 32) / 256, 256, 0, stream>>>(w_off, wofft);
    k_wt_h<<<256, 256, 0, stream>>>(w, wth);
    k_gemm_off<<<Pn / 64, 256, 0, stream>>>(cur, wofft, b_off, om);
    k_coords<<<(Pn * 9) / 256, 256, 0, stream>>>(om, sampb);
    k_gemm_main<<<Pn / 32, 256, 0, stream>>>(cur, sampb, wth, b, nxt,
                                             (l == 2) ? actf32 : nullptr);
    _Float16* tswap = cur; cur = nxt; nxt = tswap;
  }
  k_transpose<<<dim3(On / 32, HWn / 32, Bn), tb, 0, stream>>>(actf32, (float*)d_out, HWn, On);
}

// Round 3
// 515.564 us; speedup vs baseline: 2.8759x; 1.4567x over previous
//
#include <hip/hip_runtime.h>
#include <math.h>

#define Bn 4
#define Cn 256
#define Hn 64
#define Wn 64
#define On 256
#define HWn 4096
#define Pn 16384   // B*H*W
#define Kc 2304    // 9*256

typedef _Float16 half8 __attribute__((ext_vector_type(8)));
typedef float floatx4 __attribute__((ext_vector_type(4)));

// ---------------------------------------------------------------------------
// fp32 NCHW -> f16 NHWC transpose (per batch). grid (HWn/32, Cn/32, B), block (32,8)
__global__ void k_transpose_f2h(const float* __restrict__ in, _Float16* __restrict__ out,
                                int R, int Cc) {
  __shared__ float tile[32][33];
  int b = blockIdx.z;
  int c0 = blockIdx.x * 32, r0 = blockIdx.y * 32;
  const float* ib = in + (size_t)b * R * Cc;
  _Float16* ob = out + (size_t)b * R * Cc;
  int tx = threadIdx.x, ty = threadIdx.y;
#pragma unroll
  for (int i = 0; i < 32; i += 8)
    tile[ty + i][tx] = ib[(size_t)(r0 + ty + i) * Cc + (c0 + tx)];
  __syncthreads();
#pragma unroll
  for (int i = 0; i < 32; i += 8)
    ob[(size_t)(c0 + ty + i) * R + (r0 + tx)] = (_Float16)tile[tx][ty + i];
}

// fp32 NHWC -> fp32 NCHW (final output)
__global__ void k_transpose(const float* __restrict__ in, float* __restrict__ out,
                            int R, int Cc) {
  __shared__ float tile[32][33];
  int b = blockIdx.z;
  int c0 = blockIdx.x * 32, r0 = blockIdx.y * 32;
  const float* ib = in + (size_t)b * R * Cc;
  float* ob = out + (size_t)b * R * Cc;
  int tx = threadIdx.x, ty = threadIdx.y;
#pragma unroll
  for (int i = 0; i < 32; i += 8)
    tile[ty + i][tx] = ib[(size_t)(r0 + ty + i) * Cc + (c0 + tx)];
  __syncthreads();
#pragma unroll
  for (int i = 0; i < 32; i += 8)
    ob[(size_t)(c0 + ty + i) * R + (r0 + tx)] = tile[tx][ty + i];
}

// ---------------------------------------------------------------------------
// Main-conv weights: w[o][ci][3][3] -> wth[o][t*256+ci] (f16, K contiguous per o-row)
__global__ void k_wt_h(const float* __restrict__ w, _Float16* __restrict__ wth) {
  int o = blockIdx.x;
  int ci = threadIdx.x;
  const float* src = w + ((size_t)o * 256 + ci) * 9;
#pragma unroll
  for (int t = 0; t < 9; ++t)
    wth[(size_t)o * Kc + t * 256 + ci] = (_Float16)src[t];
}

// Offset-conv weights: w_off[oc(27)][ci][3][3] -> wboh[oc(32 rows, pad=0)][t*256+ci] f16
__global__ void k_wt_off_h(const float* __restrict__ w, _Float16* __restrict__ wboh) {
  int oc = blockIdx.x;    // 0..31
  int ci = threadIdx.x;   // 0..255
#pragma unroll
  for (int t = 0; t < 9; ++t)
    wboh[(size_t)oc * Kc + t * 256 + ci] =
        (oc < 27) ? (_Float16)w[((size_t)oc * 256 + ci) * 9 + t] : (_Float16)0.f;
}

// ---------------------------------------------------------------------------
// Offset conv via f16 MFMA, no LDS, no barriers.
// om[p][oc<27] = sum_{t,ci} xh[shift(p,t)][ci] * wboh[oc][t*256+ci] + boff[oc]
// grid Pn/32=512, block 256 (4 waves). wave w: mi=w&1 (16 rows), nj=w>>1 (16 cols).
// Each wave: 1 frag, K=2304 -> 72 MFMA, A+B frags direct from global (L1/L2 resident).
__global__ __launch_bounds__(256) void k_off_mfma(const _Float16* __restrict__ xh,
                                                  const _Float16* __restrict__ wboh,
                                                  const float* __restrict__ boff,
                                                  float* __restrict__ om) {
  int p0 = blockIdx.x * 32;
  int tid = threadIdx.x;
  int lane = tid & 63;
  int wave = tid >> 6;
  int mi = wave & 1;
  int nj = wave >> 1;
  int quad = lane >> 4;
  int col = lane & 15;

  int p = p0 + mi * 16 + col;       // A row (M index = col)
  int bimg = p >> 12;
  int yx = p & 4095;
  int y = yx >> 6, x = yx & 63;
  int n = nj * 16 + col;            // B row (N index = col)
  const _Float16* brow = wboh + (size_t)n * Kc + quad * 8;

  half8 zero8;
#pragma unroll
  for (int e = 0; e < 8; ++e) zero8[e] = (_Float16)0.f;

  floatx4 acc = (floatx4){0.f, 0.f, 0.f, 0.f};

  for (int t = 0; t < 9; ++t) {
    int sy = y + t / 3 - 1;
    int sx = x + t % 3 - 1;
    bool valid = (sy >= 0) & (sy < Hn) & (sx >= 0) & (sx < Wn);
    const _Float16* arow = xh +
        (size_t)(((bimg * Hn + (valid ? sy : 0)) * Wn) + (valid ? sx : 0)) * Cn + quad * 8;
    const _Float16* bp = brow + t * 256;
#pragma unroll
    for (int ci0 = 0; ci0 < 256; ci0 += 32) {
      half8 a = valid ? *(const half8*)(arow + ci0) : zero8;
      half8 b = *(const half8*)(bp + ci0);
      acc = __builtin_amdgcn_mfma_f32_16x16x32_f16(a, b, acc, 0, 0, 0);
    }
  }

  if (n < 27) {
    float bb = boff[n];
#pragma unroll
    for (int r = 0; r < 4; ++r) {
      int pp = p0 + mi * 16 + quad * 4 + r;
      om[(size_t)pp * 32 + n] = acc[r] + bb;
    }
  }
}

// ---------------------------------------------------------------------------
// Coords: om[p][32] -> samp[p][9] = {int4 corner elem-offsets; float4 folded weights}
__global__ void k_coords(const float* __restrict__ om, float* __restrict__ samp) {
  int idx = blockIdx.x * 256 + threadIdx.x;   // Pn*9
  int k = idx % 9;
  int p = idx / 9;
  int bimg = p >> 12;
  int yx = p & 4095;
  int y = yx >> 6, x = yx & 63;

  const float* o = om + (size_t)p * 32;
  float dy = o[2 * k];
  float dx = o[2 * k + 1];
  float m = 1.f / (1.f + expf(-o[18 + k]));

  float ys = (float)(y + k / 3 - 1) + dy;
  float xs = (float)(x + k % 3 - 1) + dx;
  float y0f = floorf(ys), x0f = floorf(xs);
  float wy = ys - y0f, wx = xs - x0f;
  int y0 = (int)y0f, x0 = (int)x0f;
  int y1 = y0 + 1, x1 = x0 + 1;

  bool vy0 = (y0 >= 0) & (y0 < Hn);
  bool vy1 = (y1 >= 0) & (y1 < Hn);
  bool vx0 = (x0 >= 0) & (x0 < Wn);
  bool vx1 = (x1 >= 0) & (x1 < Wn);
  int y0c = min(max(y0, 0), Hn - 1), y1c = min(max(y1, 0), Hn - 1);
  int x0c = min(max(x0, 0), Wn - 1), x1c = min(max(x1, 0), Wn - 1);

  int base = bimg * HWn;
  int o00 = (base + y0c * Wn + x0c) * Cn;
  int o01 = (base + y0c * Wn + x1c) * Cn;
  int o10 = (base + y1c * Wn + x0c) * Cn;
  int o11 = (base + y1c * Wn + x1c) * Cn;

  float w00 = (vy0 && vx0) ? m * (1.f - wy) * (1.f - wx) : 0.f;
  float w01 = (vy0 && vx1) ? m * (1.f - wy) * wx : 0.f;
  float w10 = (vy1 && vx0) ? m * wy * (1.f - wx) : 0.f;
  float w11 = (vy1 && vx1) ? m * wy * wx : 0.f;

  float* s = samp + (size_t)idx * 8;
  ((int*)s)[0] = o00; ((int*)s)[1] = o01; ((int*)s)[2] = o10; ((int*)s)[3] = o11;
  s[4] = w00; s[5] = w01; s[6] = w10; s[7] = w11;
}

// ---------------------------------------------------------------------------
// Fused deformable-gather + f16 MFMA GEMM.
// out[p][n] = relu( sum_{t,ci} bilin(p,t,ci) * wth[n][t*256+ci] + bias[n] )
// Mt=32, Nt=256(=On), BK=64. grid Pn/32=512 blocks, block 256 (4 waves).
__global__ __launch_bounds__(256) void k_gemm_main(
    const _Float16* __restrict__ xh, const float* __restrict__ samp,
    const _Float16* __restrict__ wth, const float* __restrict__ bias,
    _Float16* __restrict__ outh, float* __restrict__ outf) {
  __shared__ __align__(16) _Float16 As[32][72];   // pad 64->72 halves
  __shared__ int4 So[288];                         // samp offsets, 32 rows x 9 taps
  __shared__ float4 Sw[288];

  int p0 = blockIdx.x * 32;
  int tid = threadIdx.x;
  int lane = tid & 63;
  int wave = tid >> 6;
  int wn = wave * 64;
  int quad = lane >> 4;
  int col = lane & 15;

  {
    const float* base = samp + (size_t)p0 * 9 * 8;
    for (int e = tid; e < 288; e += 256) {
      So[e] = *(const int4*)(base + (size_t)e * 8);
      Sw[e] = *(const float4*)(base + (size_t)e * 8 + 4);
    }
  }

  float bj[4];
#pragma unroll
  for (int j = 0; j < 4; ++j) bj[j] = bias[wn + j * 16 + col];

  floatx4 acc[2][4];
#pragma unroll
  for (int i = 0; i < 2; ++i)
#pragma unroll
    for (int j = 0; j < 4; ++j) acc[i][j] = (floatx4){0.f, 0.f, 0.f, 0.f};

  int ar = tid & 31;     // A-build row
  int aseg = tid >> 5;   // 0..7 -> 8-channel segment
  int aci = aseg * 8;

  __syncthreads();

  for (int t = 0; t < 9; ++t) {
    int4 ofs = So[ar * 9 + t];
    float4 wv4 = Sw[ar * 9 + t];
    _Float16 h00 = (_Float16)wv4.x;
    _Float16 h01 = (_Float16)wv4.y;
    _Float16 h10 = (_Float16)wv4.z;
    _Float16 h11 = (_Float16)wv4.w;

    for (int ci0 = 0; ci0 < 256; ci0 += 64) {
      int kg = t * 256 + ci0;

      half8 bfrag[2][4];
#pragma unroll
      for (int kq = 0; kq < 2; ++kq)
#pragma unroll
        for (int j = 0; j < 4; ++j) {
          int n = wn + j * 16 + col;
          bfrag[kq][j] = *(const half8*)(wth + (size_t)n * Kc + kg + kq * 32 + quad * 8);
        }

      {
        int ci = ci0 + aci;
        half8 c00 = *(const half8*)(xh + (size_t)ofs.x + ci);
        half8 c01 = *(const half8*)(xh + (size_t)ofs.y + ci);
        half8 c10 = *(const half8*)(xh + (size_t)ofs.z + ci);
        half8 c11 = *(const half8*)(xh + (size_t)ofs.w + ci);
        half8 r;
#pragma unroll
        for (int e = 0; e < 8; ++e)
          r[e] = c00[e] * h00 + c01[e] * h01 + c10[e] * h10 + c11[e] * h11;
        *(half8*)&As[ar][aci] = r;
      }
      __syncthreads();

      half8 afrag[2][2];
#pragma unroll
      for (int kq = 0; kq < 2; ++kq)
#pragma unroll
        for (int i = 0; i < 2; ++i)
          afrag[kq][i] = *(const half8*)&As[i * 16 + col][kq * 32 + quad * 8];

#pragma unroll
      for (int kq = 0; kq < 2; ++kq)
#pragma unroll
        for (int i = 0; i < 2; ++i)
#pragma unroll
          for (int j = 0; j < 4; ++j)
            acc[i][j] = __builtin_amdgcn_mfma_f32_16x16x32_f16(
                afrag[kq][i], bfrag[kq][j], acc[i][j], 0, 0, 0);
      __syncthreads();
    }
  }

#pragma unroll
  for (int i = 0; i < 2; ++i)
#pragma unroll
    for (int j = 0; j < 4; ++j) {
      int n = wn + j * 16 + col;
#pragma unroll
      for (int r = 0; r < 4; ++r) {
        int p = p0 + i * 16 + quad * 4 + r;
        float v = fmaxf(acc[i][j][r] + bj[j], 0.f);
        if (outf) outf[(size_t)p * On + n] = v;
        else outh[(size_t)p * On + n] = (_Float16)v;
      }
    }
}

// ---------------------------------------------------------------------------
extern "C" void kernel_launch(void* const* d_in, const int* in_sizes, int n_in,
                              void* d_out, int out_size, void* d_ws, size_t ws_size,
                              hipStream_t stream) {
  (void)in_sizes; (void)n_in; (void)out_size; (void)ws_size;
  const float* x = (const float*)d_in[0];

  _Float16* act0h = (_Float16*)d_ws;                     // Pn*Cn f16
  _Float16* act1h = act0h + (size_t)Pn * Cn;             // Pn*Cn f16
  float* actf32   = (float*)(act1h + (size_t)Pn * Cn);   // Pn*On f32
  float* om       = actf32 + (size_t)Pn * On;            // Pn*32
  float* sampb    = om + (size_t)Pn * 32;                // Pn*9*8
  _Float16* wboh  = (_Float16*)(sampb + (size_t)Pn * 9 * 8);  // 32*Kc f16
  _Float16* wth   = wboh + (size_t)32 * Kc;              // 256*Kc f16

  dim3 tb(32, 8);
  k_transpose_f2h<<<dim3(HWn / 32, Cn / 32, Bn), tb, 0, stream>>>(x, act0h, Cn, HWn);

  _Float16* cur = act0h;
  _Float16* nxt = act1h;
  for (int l = 0; l < 3; ++l) {
    const float* w_off = (const float*)d_in[1 + l * 4];
    const float* b_off = (const float*)d_in[2 + l * 4];
    const float* w     = (const float*)d_in[3 + l * 4];
    const float* b     = (const float*)d_in[4 + l * 4];

    k_wt_off_h<<<32, 256, 0, stream>>>(w_off, wboh);
    k_wt_h<<<256, 256, 0, stream>>>(w, wth);
    k_off_mfma<<<Pn / 32, 256, 0, stream>>>(cur, wboh, b_off, om);
    k_coords<<<(Pn * 9) / 256, 256, 0, stream>>>(om, sampb);
    k_gemm_main<<<Pn / 32, 256, 0, stream>>>(cur, sampb, wth, b, nxt,
                                             (l == 2) ? actf32 : nullptr);
    _Float16* tswap = cur; cur = nxt; nxt = tswap;
  }
  k_transpose<<<dim3(On / 32, HWn / 32, Bn), tb, 0, stream>>>(actf32, (float*)d_out, HWn, On);
}

// Round 4
// 514.699 us; speedup vs baseline: 2.8807x; 1.0017x over previous
//
#include <hip/hip_runtime.h>
#include <math.h>

#define Bn 4
#define Cn 256
#define Hn 64
#define Wn 64
#define On 256
#define HWn 4096
#define Pn 16384   // B*H*W
#define Kc 2304    // 9*256

typedef _Float16 half8 __attribute__((ext_vector_type(8)));
typedef float floatx4 __attribute__((ext_vector_type(4)));

// ---------------------------------------------------------------------------
// fp32 NCHW -> f16 NHWC transpose (per batch). grid (HWn/32, Cn/32, B), block (32,8)
__global__ void k_transpose_f2h(const float* __restrict__ in, _Float16* __restrict__ out,
                                int R, int Cc) {
  __shared__ float tile[32][33];
  int b = blockIdx.z;
  int c0 = blockIdx.x * 32, r0 = blockIdx.y * 32;
  const float* ib = in + (size_t)b * R * Cc;
  _Float16* ob = out + (size_t)b * R * Cc;
  int tx = threadIdx.x, ty = threadIdx.y;
#pragma unroll
  for (int i = 0; i < 32; i += 8)
    tile[ty + i][tx] = ib[(size_t)(r0 + ty + i) * Cc + (c0 + tx)];
  __syncthreads();
#pragma unroll
  for (int i = 0; i < 32; i += 8)
    ob[(size_t)(c0 + ty + i) * R + (r0 + tx)] = (_Float16)tile[tx][ty + i];
}

// fp32 NHWC -> fp32 NCHW (final output)
__global__ void k_transpose(const float* __restrict__ in, float* __restrict__ out,
                            int R, int Cc) {
  __shared__ float tile[32][33];
  int b = blockIdx.z;
  int c0 = blockIdx.x * 32, r0 = blockIdx.y * 32;
  const float* ib = in + (size_t)b * R * Cc;
  float* ob = out + (size_t)b * R * Cc;
  int tx = threadIdx.x, ty = threadIdx.y;
#pragma unroll
  for (int i = 0; i < 32; i += 8)
    tile[ty + i][tx] = ib[(size_t)(r0 + ty + i) * Cc + (c0 + tx)];
  __syncthreads();
#pragma unroll
  for (int i = 0; i < 32; i += 8)
    ob[(size_t)(c0 + ty + i) * R + (r0 + tx)] = tile[tx][ty + i];
}

// ---------------------------------------------------------------------------
// Main-conv weights: w[o][ci][3][3] -> wth[o][t*256+ci] (f16, K contiguous per o-row)
__global__ void k_wt_h(const float* __restrict__ w, _Float16* __restrict__ wth) {
  int o = blockIdx.x;
  int ci = threadIdx.x;
  const float* src = w + ((size_t)o * 256 + ci) * 9;
#pragma unroll
  for (int t = 0; t < 9; ++t)
    wth[(size_t)o * Kc + t * 256 + ci] = (_Float16)src[t];
}

// Offset-conv weights: w_off[oc(27)][ci][3][3] -> wboh[oc(32 rows, pad=0)][t*256+ci] f16
__global__ void k_wt_off_h(const float* __restrict__ w, _Float16* __restrict__ wboh) {
  int oc = blockIdx.x;    // 0..31
  int ci = threadIdx.x;   // 0..255
#pragma unroll
  for (int t = 0; t < 9; ++t)
    wboh[(size_t)oc * Kc + t * 256 + ci] =
        (oc < 27) ? (_Float16)w[((size_t)oc * 256 + ci) * 9 + t] : (_Float16)0.f;
}

// ---------------------------------------------------------------------------
// Offset conv via f16 MFMA, no LDS, no barriers. (unchanged from R2)
__global__ __launch_bounds__(256) void k_off_mfma(const _Float16* __restrict__ xh,
                                                  const _Float16* __restrict__ wboh,
                                                  const float* __restrict__ boff,
                                                  float* __restrict__ om) {
  int p0 = blockIdx.x * 32;
  int tid = threadIdx.x;
  int lane = tid & 63;
  int wave = tid >> 6;
  int mi = wave & 1;
  int nj = wave >> 1;
  int quad = lane >> 4;
  int col = lane & 15;

  int p = p0 + mi * 16 + col;
  int bimg = p >> 12;
  int yx = p & 4095;
  int y = yx >> 6, x = yx & 63;
  int n = nj * 16 + col;
  const _Float16* brow = wboh + (size_t)n * Kc + quad * 8;

  half8 zero8;
#pragma unroll
  for (int e = 0; e < 8; ++e) zero8[e] = (_Float16)0.f;

  floatx4 acc = (floatx4){0.f, 0.f, 0.f, 0.f};

  for (int t = 0; t < 9; ++t) {
    int sy = y + t / 3 - 1;
    int sx = x + t % 3 - 1;
    bool valid = (sy >= 0) & (sy < Hn) & (sx >= 0) & (sx < Wn);
    const _Float16* arow = xh +
        (size_t)(((bimg * Hn + (valid ? sy : 0)) * Wn) + (valid ? sx : 0)) * Cn + quad * 8;
    const _Float16* bp = brow + t * 256;
#pragma unroll
    for (int ci0 = 0; ci0 < 256; ci0 += 32) {
      half8 a = valid ? *(const half8*)(arow + ci0) : zero8;
      half8 b = *(const half8*)(bp + ci0);
      acc = __builtin_amdgcn_mfma_f32_16x16x32_f16(a, b, acc, 0, 0, 0);
    }
  }

  if (n < 27) {
    float bb = boff[n];
#pragma unroll
    for (int r = 0; r < 4; ++r) {
      int pp = p0 + mi * 16 + quad * 4 + r;
      om[(size_t)pp * 32 + n] = acc[r] + bb;
    }
  }
}

// ---------------------------------------------------------------------------
// Coords: om[p][32] -> samp[p][9] = {int4 corner elem-offsets; float4 folded weights}
__global__ void k_coords(const float* __restrict__ om, float* __restrict__ samp) {
  int idx = blockIdx.x * 256 + threadIdx.x;   // Pn*9
  int k = idx % 9;
  int p = idx / 9;
  int bimg = p >> 12;
  int yx = p & 4095;
  int y = yx >> 6, x = yx & 63;

  const float* o = om + (size_t)p * 32;
  float dy = o[2 * k];
  float dx = o[2 * k + 1];
  float m = 1.f / (1.f + expf(-o[18 + k]));

  float ys = (float)(y + k / 3 - 1) + dy;
  float xs = (float)(x + k % 3 - 1) + dx;
  float y0f = floorf(ys), x0f = floorf(xs);
  float wy = ys - y0f, wx = xs - x0f;
  int y0 = (int)y0f, x0 = (int)x0f;
  int y1 = y0 + 1, x1 = x0 + 1;

  bool vy0 = (y0 >= 0) & (y0 < Hn);
  bool vy1 = (y1 >= 0) & (y1 < Hn);
  bool vx0 = (x0 >= 0) & (x0 < Wn);
  bool vx1 = (x1 >= 0) & (x1 < Wn);
  int y0c = min(max(y0, 0), Hn - 1), y1c = min(max(y1, 0), Hn - 1);
  int x0c = min(max(x0, 0), Wn - 1), x1c = min(max(x1, 0), Wn - 1);

  int base = bimg * HWn;
  int o00 = (base + y0c * Wn + x0c) * Cn;
  int o01 = (base + y0c * Wn + x1c) * Cn;
  int o10 = (base + y1c * Wn + x0c) * Cn;
  int o11 = (base + y1c * Wn + x1c) * Cn;

  float w00 = (vy0 && vx0) ? m * (1.f - wy) * (1.f - wx) : 0.f;
  float w01 = (vy0 && vx1) ? m * (1.f - wy) * wx : 0.f;
  float w10 = (vy1 && vx0) ? m * wy * (1.f - wx) : 0.f;
  float w11 = (vy1 && vx1) ? m * wy * wx : 0.f;

  float* s = samp + (size_t)idx * 8;
  ((int*)s)[0] = o00; ((int*)s)[1] = o01; ((int*)s)[2] = o10; ((int*)s)[3] = o11;
  s[4] = w00; s[5] = w01; s[6] = w10; s[7] = w11;
}

// ---------------------------------------------------------------------------
// Fused deformable-gather + f16 MFMA GEMM — software-pipelined.
// Mt=32, Nt=256, 4 waves, grid Pn/32=512. Double-buffered LDS A-tile; ONE
// barrier per 64-k chunk; gather + B prefetch for chunk c+1 issued after
// barrier(c) so they overlap chunk c's ds_reads + 16 MFMAs (the vmcnt(0)
// drain at barrier(c+1) then costs ~0 because loads had the MFMA phase to
// complete). 36 chunks fully unrolled so ping-pong buffers stay in regs.
__global__ __launch_bounds__(256, 2) void k_gemm_main(
    const _Float16* __restrict__ xh, const float* __restrict__ samp,
    const _Float16* __restrict__ wth, const float* __restrict__ bias,
    _Float16* __restrict__ outh, float* __restrict__ outf) {
  __shared__ __align__(16) _Float16 As[2][32][72];   // double buffer, pad 64->72

  int p0 = blockIdx.x * 32;
  int tid = threadIdx.x;
  int lane = tid & 63;
  int wave = tid >> 6;
  int wn = wave * 64;
  int quad = lane >> 4;
  int col = lane & 15;

  int ar = tid & 31;          // A-build row
  int aci = (tid >> 5) * 8;   // 8-channel segment

  // per-thread samp base for row ar (int4 offsets + float4 weights per tap)
  const float* smp = samp + (size_t)(p0 + ar) * 9 * 8;

  const _Float16* wrow[4];
#pragma unroll
  for (int j = 0; j < 4; ++j)
    wrow[j] = wth + (size_t)(wn + j * 16 + col) * Kc + quad * 8;

  float bj[4];
#pragma unroll
  for (int j = 0; j < 4; ++j) bj[j] = bias[wn + j * 16 + col];

  floatx4 acc[2][4];
#pragma unroll
  for (int i = 0; i < 2; ++i)
#pragma unroll
    for (int j = 0; j < 4; ++j) acc[i][j] = (floatx4){0.f, 0.f, 0.f, 0.f};

  half8 bb[2][2][4];          // B ping-pong
  half8 g00, g01, g10, g11;   // gather prefetch
  int4 ofs;
  float4 wv;

  // ---- prologue: chunk 0 (t=0, ci0=0)
  ofs = *(const int4*)(smp);
  wv = *(const float4*)(smp + 4);
  g00 = *(const half8*)(xh + (size_t)ofs.x + aci);
  g01 = *(const half8*)(xh + (size_t)ofs.y + aci);
  g10 = *(const half8*)(xh + (size_t)ofs.z + aci);
  g11 = *(const half8*)(xh + (size_t)ofs.w + aci);
#pragma unroll
  for (int kq = 0; kq < 2; ++kq)
#pragma unroll
    for (int j = 0; j < 4; ++j)
      bb[0][kq][j] = *(const half8*)(wrow[j] + kq * 32);

#pragma unroll
  for (int c = 0; c < 36; ++c) {
    int buf = c & 1;
    // combine prefetched corners -> LDS
    {
      _Float16 h00 = (_Float16)wv.x, h01 = (_Float16)wv.y;
      _Float16 h10 = (_Float16)wv.z, h11 = (_Float16)wv.w;
      half8 r;
#pragma unroll
      for (int e = 0; e < 8; ++e)
        r[e] = g00[e] * h00 + g01[e] * h01 + g10[e] * h10 + g11[e] * h11;
      *(half8*)&As[buf][ar][aci] = r;
    }
    __syncthreads();

    // prefetch chunk c+1 (overlaps this chunk's ds_reads + MFMAs)
    if (c < 35) {
      int cn = c + 1;
      int tn = cn >> 2;
      int cin = (cn & 3) * 64;
      if ((cn & 3) == 0) {
        ofs = *(const int4*)(smp + tn * 8);
        wv = *(const float4*)(smp + tn * 8 + 4);
      }
      int ci = cin + aci;
      g00 = *(const half8*)(xh + (size_t)ofs.x + ci);
      g01 = *(const half8*)(xh + (size_t)ofs.y + ci);
      g10 = *(const half8*)(xh + (size_t)ofs.z + ci);
      g11 = *(const half8*)(xh + (size_t)ofs.w + ci);
      int kg = tn * 256 + cin;
#pragma unroll
      for (int kq = 0; kq < 2; ++kq)
#pragma unroll
        for (int j = 0; j < 4; ++j)
          bb[cn & 1][kq][j] = *(const half8*)(wrow[j] + kg + kq * 32);
    }

    half8 af[2][2];
#pragma unroll
    for (int kq = 0; kq < 2; ++kq)
#pragma unroll
      for (int i = 0; i < 2; ++i)
        af[kq][i] = *(const half8*)&As[buf][i * 16 + col][kq * 32 + quad * 8];

#pragma unroll
    for (int kq = 0; kq < 2; ++kq)
#pragma unroll
      for (int i = 0; i < 2; ++i)
#pragma unroll
        for (int j = 0; j < 4; ++j)
          acc[i][j] = __builtin_amdgcn_mfma_f32_16x16x32_f16(
              af[kq][i], bb[buf][kq][j], acc[i][j], 0, 0, 0);
  }

  // epilogue: bias + relu; f16 activations (or fp32 for the last layer)
#pragma unroll
  for (int i = 0; i < 2; ++i)
#pragma unroll
    for (int j = 0; j < 4; ++j) {
      int n = wn + j * 16 + col;
#pragma unroll
      for (int r = 0; r < 4; ++r) {
        int p = p0 + i * 16 + quad * 4 + r;
        float v = fmaxf(acc[i][j][r] + bj[j], 0.f);
        if (outf) outf[(size_t)p * On + n] = v;
        else outh[(size_t)p * On + n] = (_Float16)v;
      }
    }
}

// ---------------------------------------------------------------------------
extern "C" void kernel_launch(void* const* d_in, const int* in_sizes, int n_in,
                              void* d_out, int out_size, void* d_ws, size_t ws_size,
                              hipStream_t stream) {
  (void)in_sizes; (void)n_in; (void)out_size; (void)ws_size;
  const float* x = (const float*)d_in[0];

  _Float16* act0h = (_Float16*)d_ws;                     // Pn*Cn f16
  _Float16* act1h = act0h + (size_t)Pn * Cn;             // Pn*Cn f16
  float* actf32   = (float*)(act1h + (size_t)Pn * Cn);   // Pn*On f32
  float* om       = actf32 + (size_t)Pn * On;            // Pn*32
  float* sampb    = om + (size_t)Pn * 32;                // Pn*9*8
  _Float16* wboh  = (_Float16*)(sampb + (size_t)Pn * 9 * 8);  // 32*Kc f16
  _Float16* wth   = wboh + (size_t)32 * Kc;              // 256*Kc f16

  dim3 tb(32, 8);
  k_transpose_f2h<<<dim3(HWn / 32, Cn / 32, Bn), tb, 0, stream>>>(x, act0h, Cn, HWn);

  _Float16* cur = act0h;
  _Float16* nxt = act1h;
  for (int l = 0; l < 3; ++l) {
    const float* w_off = (const float*)d_in[1 + l * 4];
    const float* b_off = (const float*)d_in[2 + l * 4];
    const float* w     = (const float*)d_in[3 + l * 4];
    const float* b     = (const float*)d_in[4 + l * 4];

    k_wt_off_h<<<32, 256, 0, stream>>>(w_off, wboh);
    k_wt_h<<<256, 256, 0, stream>>>(w, wth);
    k_off_mfma<<<Pn / 32, 256, 0, stream>>>(cur, wboh, b_off, om);
    k_coords<<<(Pn * 9) / 256, 256, 0, stream>>>(om, sampb);
    k_gemm_main<<<Pn / 32, 256, 0, stream>>>(cur, sampb, wth, b, nxt,
                                             (l == 2) ? actf32 : nullptr);
    _Float16* tswap = cur; cur = nxt; nxt = tswap;
  }
  k_transpose<<<dim3(On / 32, HWn / 32, Bn), tb, 0, stream>>>(actf32, (float*)d_out, HWn, On);
}

// Round 5
// 332.466 us; speedup vs baseline: 4.4597x; 1.5481x over previous
//
#include <hip/hip_runtime.h>
#include <math.h>

#define Bn 4
#define Cn 256
#define Hn 64
#define Wn 64
#define On 256
#define HWn 4096
#define Pn 16384   // B*H*W
#define Kc 2304    // 9*256

typedef _Float16 half8 __attribute__((ext_vector_type(8)));
typedef float floatx4 __attribute__((ext_vector_type(4)));

// ---------------------------------------------------------------------------
// fp32 NCHW -> f16 NHWC transpose (per batch). grid (HWn/32, Cn/32, B), block (32,8)
__global__ void k_transpose_f2h(const float* __restrict__ in, _Float16* __restrict__ out,
                                int R, int Cc) {
  __shared__ float tile[32][33];
  int b = blockIdx.z;
  int c0 = blockIdx.x * 32, r0 = blockIdx.y * 32;
  const float* ib = in + (size_t)b * R * Cc;
  _Float16* ob = out + (size_t)b * R * Cc;
  int tx = threadIdx.x, ty = threadIdx.y;
#pragma unroll
  for (int i = 0; i < 32; i += 8)
    tile[ty + i][tx] = ib[(size_t)(r0 + ty + i) * Cc + (c0 + tx)];
  __syncthreads();
#pragma unroll
  for (int i = 0; i < 32; i += 8)
    ob[(size_t)(c0 + ty + i) * R + (r0 + tx)] = (_Float16)tile[tx][ty + i];
}

// fp32 NHWC -> fp32 NCHW (final output)
__global__ void k_transpose(const float* __restrict__ in, float* __restrict__ out,
                            int R, int Cc) {
  __shared__ float tile[32][33];
  int b = blockIdx.z;
  int c0 = blockIdx.x * 32, r0 = blockIdx.y * 32;
  const float* ib = in + (size_t)b * R * Cc;
  float* ob = out + (size_t)b * R * Cc;
  int tx = threadIdx.x, ty = threadIdx.y;
#pragma unroll
  for (int i = 0; i < 32; i += 8)
    tile[ty + i][tx] = ib[(size_t)(r0 + ty + i) * Cc + (c0 + tx)];
  __syncthreads();
#pragma unroll
  for (int i = 0; i < 32; i += 8)
    ob[(size_t)(c0 + ty + i) * R + (r0 + tx)] = tile[tx][ty + i];
}

// ---------------------------------------------------------------------------
// Main-conv weights packed for coalesced MFMA B-frag loads.
// w[o][ci][3][3] fp32 -> wtp f16: for chunk c = t*4 + ci/64 (64-k window),
// group g = n>>4, kq = (k%64)/32: a 1KB block where lane (quad=l>>4,col=l&15)
// reads 16B at slot l: elements B[n = g*16+col][k = kq*32 + quad*8 + e].
// grid 256 (n), block 256 (ci).
__global__ void k_wt_pack(const float* __restrict__ w, _Float16* __restrict__ wtp) {
  int n = blockIdx.x;
  int ci = threadIdx.x;
  int g = n >> 4, col = n & 15;
  int cq = ci >> 6;           // which 64-k window within the tap
  int kk = ci & 63;
  int kq = kk >> 5;
  int k32 = kk & 31;
  int quad = k32 >> 3;
  int e = k32 & 7;
  const float* src = w + (size_t)n * 2304 + (size_t)ci * 9;
#pragma unroll
  for (int t = 0; t < 9; ++t) {
    int c = t * 4 + cq;
    size_t dst = ((size_t)((c * 16 + g) * 2 + kq)) * 512 + (quad * 16 + col) * 8 + e;
    wtp[dst] = (_Float16)src[t];
  }
}

// Offset-conv weights: w_off[oc(27)][ci][3][3] -> wboh[oc(32 rows, pad=0)][t*256+ci] f16
__global__ void k_wt_off_h(const float* __restrict__ w, _Float16* __restrict__ wboh) {
  int oc = blockIdx.x;    // 0..31
  int ci = threadIdx.x;   // 0..255
#pragma unroll
  for (int t = 0; t < 9; ++t)
    wboh[(size_t)oc * Kc + t * 256 + ci] =
        (oc < 27) ? (_Float16)w[((size_t)oc * 256 + ci) * 9 + t] : (_Float16)0.f;
}

// ---------------------------------------------------------------------------
// Offset conv via f16 MFMA, no LDS, no barriers. (unchanged from R2)
__global__ __launch_bounds__(256) void k_off_mfma(const _Float16* __restrict__ xh,
                                                  const _Float16* __restrict__ wboh,
                                                  const float* __restrict__ boff,
                                                  float* __restrict__ om) {
  int p0 = blockIdx.x * 32;
  int tid = threadIdx.x;
  int lane = tid & 63;
  int wave = tid >> 6;
  int mi = wave & 1;
  int nj = wave >> 1;
  int quad = lane >> 4;
  int col = lane & 15;

  int p = p0 + mi * 16 + col;
  int bimg = p >> 12;
  int yx = p & 4095;
  int y = yx >> 6, x = yx & 63;
  int n = nj * 16 + col;
  const _Float16* brow = wboh + (size_t)n * Kc + quad * 8;

  half8 zero8;
#pragma unroll
  for (int e = 0; e < 8; ++e) zero8[e] = (_Float16)0.f;

  floatx4 acc = (floatx4){0.f, 0.f, 0.f, 0.f};

  for (int t = 0; t < 9; ++t) {
    int sy = y + t / 3 - 1;
    int sx = x + t % 3 - 1;
    bool valid = (sy >= 0) & (sy < Hn) & (sx >= 0) & (sx < Wn);
    const _Float16* arow = xh +
        (size_t)(((bimg * Hn + (valid ? sy : 0)) * Wn) + (valid ? sx : 0)) * Cn + quad * 8;
    const _Float16* bp = brow + t * 256;
#pragma unroll
    for (int ci0 = 0; ci0 < 256; ci0 += 32) {
      half8 a = valid ? *(const half8*)(arow + ci0) : zero8;
      half8 b = *(const half8*)(bp + ci0);
      acc = __builtin_amdgcn_mfma_f32_16x16x32_f16(a, b, acc, 0, 0, 0);
    }
  }

  if (n < 27) {
    float bb = boff[n];
#pragma unroll
    for (int r = 0; r < 4; ++r) {
      int pp = p0 + mi * 16 + quad * 4 + r;
      om[(size_t)pp * 32 + n] = acc[r] + bb;
    }
  }
}

// ---------------------------------------------------------------------------
// Coords: om[p][32] -> samp[p][9] = {int4 corner elem-offsets; float4 folded weights}
__global__ void k_coords(const float* __restrict__ om, float* __restrict__ samp) {
  int idx = blockIdx.x * 256 + threadIdx.x;   // Pn*9
  int k = idx % 9;
  int p = idx / 9;
  int bimg = p >> 12;
  int yx = p & 4095;
  int y = yx >> 6, x = yx & 63;

  const float* o = om + (size_t)p * 32;
  float dy = o[2 * k];
  float dx = o[2 * k + 1];
  float m = 1.f / (1.f + expf(-o[18 + k]));

  float ys = (float)(y + k / 3 - 1) + dy;
  float xs = (float)(x + k % 3 - 1) + dx;
  float y0f = floorf(ys), x0f = floorf(xs);
  float wy = ys - y0f, wx = xs - x0f;
  int y0 = (int)y0f, x0 = (int)x0f;
  int y1 = y0 + 1, x1 = x0 + 1;

  bool vy0 = (y0 >= 0) & (y0 < Hn);
  bool vy1 = (y1 >= 0) & (y1 < Hn);
  bool vx0 = (x0 >= 0) & (x0 < Wn);
  bool vx1 = (x1 >= 0) & (x1 < Wn);
  int y0c = min(max(y0, 0), Hn - 1), y1c = min(max(y1, 0), Hn - 1);
  int x0c = min(max(x0, 0), Wn - 1), x1c = min(max(x1, 0), Wn - 1);

  int base = bimg * HWn;
  int o00 = (base + y0c * Wn + x0c) * Cn;
  int o01 = (base + y0c * Wn + x1c) * Cn;
  int o10 = (base + y1c * Wn + x0c) * Cn;
  int o11 = (base + y1c * Wn + x1c) * Cn;

  float w00 = (vy0 && vx0) ? m * (1.f - wy) * (1.f - wx) : 0.f;
  float w01 = (vy0 && vx1) ? m * (1.f - wy) * wx : 0.f;
  float w10 = (vy1 && vx0) ? m * wy * (1.f - wx) : 0.f;
  float w11 = (vy1 && vx1) ? m * wy * wx : 0.f;

  float* s = samp + (size_t)idx * 8;
  ((int*)s)[0] = o00; ((int*)s)[1] = o01; ((int*)s)[2] = o10; ((int*)s)[3] = o11;
  s[4] = w00; s[5] = w01; s[6] = w10; s[7] = w11;
}

// ---------------------------------------------------------------------------
// Fused deformable-gather + f16 MFMA GEMM — software-pipelined, request-coalesced.
// Mt=32, Nt=256, 4 waves, grid Pn/32=512. Gather mapping ar=tid>>3/aseg=tid&7:
// a wave's corner-load = 8 rows x contiguous 128B line = 8 lines (was 32).
// B from packed wtp: each wave-load = contiguous 1KB = 8 lines (was 16).
__global__ __launch_bounds__(256, 2) void k_gemm_main(
    const _Float16* __restrict__ xh, const float* __restrict__ samp,
    const _Float16* __restrict__ wtp, const float* __restrict__ bias,
    _Float16* __restrict__ outh, float* __restrict__ outf) {
  __shared__ __align__(16) _Float16 As[2][32][72];   // double buffer, pad 64->72

  int p0 = blockIdx.x * 32;
  int tid = threadIdx.x;
  int lane = tid & 63;
  int wave = tid >> 6;
  int wn = wave * 64;
  int quad = lane >> 4;
  int col = lane & 15;

  int ar = tid >> 3;          // A-build row (8 threads per row)
  int aci = (tid & 7) * 8;    // 8-channel segment

  const float* smp = samp + (size_t)(p0 + ar) * 9 * 8;

  // packed-B base for this wave: groups g = wave*4 + j
  const _Float16* wb = wtp + (size_t)lane * 8;

  float bj[4];
#pragma unroll
  for (int j = 0; j < 4; ++j) bj[j] = bias[wn + j * 16 + col];

  floatx4 acc[2][4];
#pragma unroll
  for (int i = 0; i < 2; ++i)
#pragma unroll
    for (int j = 0; j < 4; ++j) acc[i][j] = (floatx4){0.f, 0.f, 0.f, 0.f};

  half8 bb[2][2][4];          // B ping-pong
  half8 g00, g01, g10, g11;   // gather prefetch
  int4 ofs;
  float4 wv;

  // ---- prologue: chunk 0 (t=0, ci0=0)
  ofs = *(const int4*)(smp);
  wv = *(const float4*)(smp + 4);
  g00 = *(const half8*)(xh + (size_t)ofs.x + aci);
  g01 = *(const half8*)(xh + (size_t)ofs.y + aci);
  g10 = *(const half8*)(xh + (size_t)ofs.z + aci);
  g11 = *(const half8*)(xh + (size_t)ofs.w + aci);
#pragma unroll
  for (int kq = 0; kq < 2; ++kq)
#pragma unroll
    for (int j = 0; j < 4; ++j)
      bb[0][kq][j] = *(const half8*)(wb + (size_t)(((0 * 16 + wave * 4 + j) * 2 + kq)) * 512);

#pragma unroll
  for (int c = 0; c < 36; ++c) {
    int buf = c & 1;
    // combine prefetched corners -> LDS
    {
      _Float16 h00 = (_Float16)wv.x, h01 = (_Float16)wv.y;
      _Float16 h10 = (_Float16)wv.z, h11 = (_Float16)wv.w;
      half8 r;
#pragma unroll
      for (int e = 0; e < 8; ++e)
        r[e] = g00[e] * h00 + g01[e] * h01 + g10[e] * h10 + g11[e] * h11;
      *(half8*)&As[buf][ar][aci] = r;
    }
    __syncthreads();

    // prefetch chunk c+1 (overlaps this chunk's ds_reads + MFMAs)
    if (c < 35) {
      int cn = c + 1;
      int tn = cn >> 2;
      int cin = (cn & 3) * 64;
      if ((cn & 3) == 0) {
        ofs = *(const int4*)(smp + tn * 8);
        wv = *(const float4*)(smp + tn * 8 + 4);
      }
      int ci = cin + aci;
      g00 = *(const half8*)(xh + (size_t)ofs.x + ci);
      g01 = *(const half8*)(xh + (size_t)ofs.y + ci);
      g10 = *(const half8*)(xh + (size_t)ofs.z + ci);
      g11 = *(const half8*)(xh + (size_t)ofs.w + ci);
#pragma unroll
      for (int kq = 0; kq < 2; ++kq)
#pragma unroll
        for (int j = 0; j < 4; ++j)
          bb[cn & 1][kq][j] =
              *(const half8*)(wb + (size_t)(((cn * 16 + wave * 4 + j) * 2 + kq)) * 512);
    }

    half8 af[2][2];
#pragma unroll
    for (int kq = 0; kq < 2; ++kq)
#pragma unroll
      for (int i = 0; i < 2; ++i)
        af[kq][i] = *(const half8*)&As[buf][i * 16 + col][kq * 32 + quad * 8];

#pragma unroll
    for (int kq = 0; kq < 2; ++kq)
#pragma unroll
      for (int i = 0; i < 2; ++i)
#pragma unroll
        for (int j = 0; j < 4; ++j)
          acc[i][j] = __builtin_amdgcn_mfma_f32_16x16x32_f16(
              af[kq][i], bb[buf][kq][j], acc[i][j], 0, 0, 0);
  }

  // epilogue: bias + relu; f16 activations (or fp32 for the last layer)
#pragma unroll
  for (int i = 0; i < 2; ++i)
#pragma unroll
    for (int j = 0; j < 4; ++j) {
      int n = wn + j * 16 + col;
#pragma unroll
      for (int r = 0; r < 4; ++r) {
        int p = p0 + i * 16 + quad * 4 + r;
        float v = fmaxf(acc[i][j][r] + bj[j], 0.f);
        if (outf) outf[(size_t)p * On + n] = v;
        else outh[(size_t)p * On + n] = (_Float16)v;
      }
    }
}

// ---------------------------------------------------------------------------
extern "C" void kernel_launch(void* const* d_in, const int* in_sizes, int n_in,
                              void* d_out, int out_size, void* d_ws, size_t ws_size,
                              hipStream_t stream) {
  (void)in_sizes; (void)n_in; (void)out_size; (void)ws_size;
  const float* x = (const float*)d_in[0];

  _Float16* act0h = (_Float16*)d_ws;                     // Pn*Cn f16
  _Float16* act1h = act0h + (size_t)Pn * Cn;             // Pn*Cn f16
  float* actf32   = (float*)(act1h + (size_t)Pn * Cn);   // Pn*On f32
  float* om       = actf32 + (size_t)Pn * On;            // Pn*32
  float* sampb    = om + (size_t)Pn * 32;                // Pn*9*8
  _Float16* wboh  = (_Float16*)(sampb + (size_t)Pn * 9 * 8);  // 32*Kc f16
  _Float16* wtp   = wboh + (size_t)32 * Kc;              // 256*Kc f16 (packed)

  dim3 tb(32, 8);
  k_transpose_f2h<<<dim3(HWn / 32, Cn / 32, Bn), tb, 0, stream>>>(x, act0h, Cn, HWn);

  _Float16* cur = act0h;
  _Float16* nxt = act1h;
  for (int l = 0; l < 3; ++l) {
    const float* w_off = (const float*)d_in[1 + l * 4];
    const float* b_off = (const float*)d_in[2 + l * 4];
    const float* w     = (const float*)d_in[3 + l * 4];
    const float* b     = (const float*)d_in[4 + l * 4];

    k_wt_off_h<<<32, 256, 0, stream>>>(w_off, wboh);
    k_wt_pack<<<256, 256, 0, stream>>>(w, wtp);
    k_off_mfma<<<Pn / 32, 256, 0, stream>>>(cur, wboh, b_off, om);
    k_coords<<<(Pn * 9) / 256, 256, 0, stream>>>(om, sampb);
    k_gemm_main<<<Pn / 32, 256, 0, stream>>>(cur, sampb, wtp, b, nxt,
                                             (l == 2) ? actf32 : nullptr);
    _Float16* tswap = cur; cur = nxt; nxt = tswap;
  }
  k_transpose<<<dim3(On / 32, HWn / 32, Bn), tb, 0, stream>>>(actf32, (float*)d_out, HWn, On);
}

// Round 6
// 302.375 us; speedup vs baseline: 4.9035x; 1.0995x over previous
//
#include <hip/hip_runtime.h>
#include <math.h>

#define Bn 4
#define Cn 256
#define Hn 64
#define Wn 64
#define On 256
#define HWn 4096
#define Pn 16384   // B*H*W
#define Kc 2304    // 9*256

typedef _Float16 half8 __attribute__((ext_vector_type(8)));
typedef float floatx4 __attribute__((ext_vector_type(4)));

// ---------------------------------------------------------------------------
// fp32 NCHW -> f16 NHWC transpose (per batch). grid (HWn/32, Cn/32, B), block (32,8)
__global__ void k_transpose_f2h(const float* __restrict__ in, _Float16* __restrict__ out,
                                int R, int Cc) {
  __shared__ float tile[32][33];
  int b = blockIdx.z;
  int c0 = blockIdx.x * 32, r0 = blockIdx.y * 32;
  const float* ib = in + (size_t)b * R * Cc;
  _Float16* ob = out + (size_t)b * R * Cc;
  int tx = threadIdx.x, ty = threadIdx.y;
#pragma unroll
  for (int i = 0; i < 32; i += 8)
    tile[ty + i][tx] = ib[(size_t)(r0 + ty + i) * Cc + (c0 + tx)];
  __syncthreads();
#pragma unroll
  for (int i = 0; i < 32; i += 8)
    ob[(size_t)(c0 + ty + i) * R + (r0 + tx)] = (_Float16)tile[tx][ty + i];
}

// fp32 NHWC -> fp32 NCHW (final output)
__global__ void k_transpose(const float* __restrict__ in, float* __restrict__ out,
                            int R, int Cc) {
  __shared__ float tile[32][33];
  int b = blockIdx.z;
  int c0 = blockIdx.x * 32, r0 = blockIdx.y * 32;
  const float* ib = in + (size_t)b * R * Cc;
  float* ob = out + (size_t)b * R * Cc;
  int tx = threadIdx.x, ty = threadIdx.y;
#pragma unroll
  for (int i = 0; i < 32; i += 8)
    tile[ty + i][tx] = ib[(size_t)(r0 + ty + i) * Cc + (c0 + tx)];
  __syncthreads();
#pragma unroll
  for (int i = 0; i < 32; i += 8)
    ob[(size_t)(c0 + ty + i) * R + (r0 + tx)] = tile[tx][ty + i];
}

// ---------------------------------------------------------------------------
// Main-conv weights packed: chunk c = t*4 + ci/64; within chunk, group g=n>>4,
// kq: 1KB block where lane (quad,col) holds B[n=g*16+col][k=kq*32+quad*8+e].
// Chunk c occupies wtp[c*16384 .. c*16384+16383] (chunk-contiguous -> stageable).
__global__ void k_wt_pack(const float* __restrict__ w, _Float16* __restrict__ wtp) {
  int n = blockIdx.x;
  int ci = threadIdx.x;
  int g = n >> 4, col = n & 15;
  int cq = ci >> 6;
  int kk = ci & 63;
  int kq = kk >> 5;
  int k32 = kk & 31;
  int quad = k32 >> 3;
  int e = k32 & 7;
  const float* src = w + (size_t)n * 2304 + (size_t)ci * 9;
#pragma unroll
  for (int t = 0; t < 9; ++t) {
    int c = t * 4 + cq;
    size_t dst = ((size_t)((c * 16 + g) * 2 + kq)) * 512 + (quad * 16 + col) * 8 + e;
    wtp[dst] = (_Float16)src[t];
  }
}

// Offset-conv weights packed, N padded to 32 (2 groups): chunk c = t*4+cw is
// contiguous 2048 halves: ((c*2+g)*2+kq)*512 + (quad*16+col)*8 + e.
__global__ void k_wt_off_pack(const float* __restrict__ w, _Float16* __restrict__ wbop) {
  int n = blockIdx.x;     // 0..31
  int ci = threadIdx.x;   // 0..255
  int g = n >> 4, col = n & 15;
  int cw = ci >> 6;
  int r = ci & 63;
  int kq = r >> 5;
  int r2 = r & 31;
  int quad = r2 >> 3;
  int e = r2 & 7;
#pragma unroll
  for (int t = 0; t < 9; ++t) {
    int c = t * 4 + cw;
    size_t dst = ((size_t)((c * 2 + g) * 2 + kq)) * 512 + (quad * 16 + col) * 8 + e;
    wbop[dst] = (n < 27) ? (_Float16)w[((size_t)n * 256 + ci) * 9 + t] : (_Float16)0.f;
  }
}

// ---------------------------------------------------------------------------
// Offset conv via f16 MFMA — LDS-staged, request-coalesced, 2-barrier pipeline.
// Mt=32, Nt=32, grid Pn/32=512, block 256 (4 waves = 2m x 2n).
// Per chunk: A = 32 contiguous 128B rows (shifted window), B = 4KB staged once.
__global__ __launch_bounds__(256, 4) void k_off_mfma(const _Float16* __restrict__ xh,
                                                     const _Float16* __restrict__ wbop,
                                                     const float* __restrict__ boff,
                                                     float* __restrict__ om) {
  __shared__ __align__(16) _Float16 Ao[32][72];
  __shared__ __align__(16) _Float16 Bo[2048];

  int p0 = blockIdx.x * 32;
  int tid = threadIdx.x;
  int lane = tid & 63;
  int wave = tid >> 6;
  int mg = wave >> 1;
  int ng = wave & 1;
  int quad = lane >> 4;
  int col = lane & 15;

  int ar = tid >> 3;          // staging row 0..31
  int aci = (tid & 7) * 8;

  int p = p0 + ar;
  int bimg = p >> 12;
  int yx = p & 4095;
  int y = yx >> 6, x = yx & 63;

  half8 zero8;
#pragma unroll
  for (int e = 0; e < 8; ++e) zero8[e] = (_Float16)0.f;

  floatx4 acc = (floatx4){0.f, 0.f, 0.f, 0.f};

  half8 ga, gb;
  int abase = 0;
  bool avalid = false;

  // prologue: chunk 0 = tap 0 (dy=-1,dx=-1), ci-window 0
  {
    int sy = y - 1, sx = x - 1;
    avalid = (sy >= 0) & (sy < Hn) & (sx >= 0) & (sx < Wn);
    abase = (((bimg * Hn + (avalid ? sy : 0)) * Wn) + (avalid ? sx : 0)) * Cn;
    ga = zero8;
    if (avalid) ga = *(const half8*)(xh + (size_t)abase + aci);
    gb = *(const half8*)(wbop + (size_t)tid * 8);
  }

#pragma unroll
  for (int c = 0; c < 36; ++c) {
    __syncthreads();   // prior frag reads complete
    *(half8*)&Ao[ar][aci] = ga;
    *(half8*)&Bo[tid * 8] = gb;
    __syncthreads();   // staged data visible

    if (c < 35) {
      int cn = c + 1;
      int tn = cn >> 2;
      int cin = (cn & 3) * 64;
      if ((cn & 3) == 0) {
        int sy = y + tn / 3 - 1;
        int sx = x + tn % 3 - 1;
        avalid = (sy >= 0) & (sy < Hn) & (sx >= 0) & (sx < Wn);
        abase = (((bimg * Hn + (avalid ? sy : 0)) * Wn) + (avalid ? sx : 0)) * Cn;
      }
      ga = zero8;
      if (avalid) ga = *(const half8*)(xh + (size_t)abase + cin + aci);
      gb = *(const half8*)(wbop + (size_t)cn * 2048 + tid * 8);
    }

    half8 af[2], bf[2];
#pragma unroll
    for (int kq = 0; kq < 2; ++kq) {
      af[kq] = *(const half8*)&Ao[mg * 16 + col][kq * 32 + quad * 8];
      bf[kq] = *(const half8*)&Bo[(ng * 2 + kq) * 512 + lane * 8];
    }
#pragma unroll
    for (int kq = 0; kq < 2; ++kq)
      acc = __builtin_amdgcn_mfma_f32_16x16x32_f16(af[kq], bf[kq], acc, 0, 0, 0);
  }

  int n = ng * 16 + col;
  if (n < 27) {
    float bb = boff[n];
#pragma unroll
    for (int r = 0; r < 4; ++r) {
      int pp = p0 + mg * 16 + quad * 4 + r;
      om[(size_t)pp * 32 + n] = acc[r] + bb;
    }
  }
}

// ---------------------------------------------------------------------------
// Coords: om[p][32] -> samp[p][9] = {int4 corner elem-offsets; float4 folded weights}
__global__ void k_coords(const float* __restrict__ om, float* __restrict__ samp) {
  int idx = blockIdx.x * 256 + threadIdx.x;   // Pn*9
  int k = idx % 9;
  int p = idx / 9;
  int bimg = p >> 12;
  int yx = p & 4095;
  int y = yx >> 6, x = yx & 63;

  const float* o = om + (size_t)p * 32;
  float dy = o[2 * k];
  float dx = o[2 * k + 1];
  float m = 1.f / (1.f + expf(-o[18 + k]));

  float ys = (float)(y + k / 3 - 1) + dy;
  float xs = (float)(x + k % 3 - 1) + dx;
  float y0f = floorf(ys), x0f = floorf(xs);
  float wy = ys - y0f, wx = xs - x0f;
  int y0 = (int)y0f, x0 = (int)x0f;
  int y1 = y0 + 1, x1 = x0 + 1;

  bool vy0 = (y0 >= 0) & (y0 < Hn);
  bool vy1 = (y1 >= 0) & (y1 < Hn);
  bool vx0 = (x0 >= 0) & (x0 < Wn);
  bool vx1 = (x1 >= 0) & (x1 < Wn);
  int y0c = min(max(y0, 0), Hn - 1), y1c = min(max(y1, 0), Hn - 1);
  int x0c = min(max(x0, 0), Wn - 1), x1c = min(max(x1, 0), Wn - 1);

  int base = bimg * HWn;
  int o00 = (base + y0c * Wn + x0c) * Cn;
  int o01 = (base + y0c * Wn + x1c) * Cn;
  int o10 = (base + y1c * Wn + x0c) * Cn;
  int o11 = (base + y1c * Wn + x1c) * Cn;

  float w00 = (vy0 && vx0) ? m * (1.f - wy) * (1.f - wx) : 0.f;
  float w01 = (vy0 && vx1) ? m * (1.f - wy) * wx : 0.f;
  float w10 = (vy1 && vx0) ? m * wy * (1.f - wx) : 0.f;
  float w11 = (vy1 && vx1) ? m * wy * wx : 0.f;

  float* s = samp + (size_t)idx * 8;
  ((int*)s)[0] = o00; ((int*)s)[1] = o01; ((int*)s)[2] = o10; ((int*)s)[3] = o11;
  s[4] = w00; s[5] = w01; s[6] = w10; s[7] = w11;
}

// ---------------------------------------------------------------------------
// Fused deformable-gather + f16 MFMA GEMM.
// Mt=64, Nt=256, 512 threads (8 waves = 2m x 4n), grid Pn/64=256 (1 block/CU).
// B staged through LDS once per chunk (dedupes the per-wave B re-reads that
// dominated R5's request count); A gathered+bilinear-combined into LDS.
// Single-buffered LDS, 2 barriers/chunk; global prefetch-to-regs issued
// between barrier2 and the MFMAs so load latency hides under compute.
__global__ __launch_bounds__(512, 2) void k_gemm_main(
    const _Float16* __restrict__ xh, const float* __restrict__ samp,
    const _Float16* __restrict__ wtp, const float* __restrict__ bias,
    _Float16* __restrict__ outh, float* __restrict__ outf) {
  __shared__ __align__(16) _Float16 As[64][72];    // 9.2 KB
  __shared__ __align__(16) _Float16 Bs[16384];     // 32 KB

  int p0 = blockIdx.x * 64;
  int tid = threadIdx.x;       // 0..511
  int lane = tid & 63;
  int wave = tid >> 6;         // 0..7
  int quad = lane >> 4;
  int col = lane & 15;
  int mw = wave >> 2;          // 0..1 (32-row half)
  int nw = wave & 3;           // 0..3 (64-col group)

  int ar = tid >> 3;           // gather row 0..63
  int aci = (tid & 7) * 8;     // 8-channel segment

  const float* smp = samp + (size_t)(p0 + ar) * 72;

  float bj[4];
#pragma unroll
  for (int j = 0; j < 4; ++j) bj[j] = bias[(nw * 4 + j) * 16 + col];

  floatx4 acc[2][4];
#pragma unroll
  for (int i = 0; i < 2; ++i)
#pragma unroll
    for (int j = 0; j < 4; ++j) acc[i][j] = (floatx4){0.f, 0.f, 0.f, 0.f};

  half8 g00, g01, g10, g11;
  half8 bst[4];
  int4 ofs;
  float4 wv;

  // prologue: chunk 0
  ofs = *(const int4*)(smp);
  wv = *(const float4*)(smp + 4);
  g00 = *(const half8*)(xh + (size_t)ofs.x + aci);
  g01 = *(const half8*)(xh + (size_t)ofs.y + aci);
  g10 = *(const half8*)(xh + (size_t)ofs.z + aci);
  g11 = *(const half8*)(xh + (size_t)ofs.w + aci);
#pragma unroll
  for (int q = 0; q < 4; ++q)
    bst[q] = *(const half8*)(wtp + (size_t)(q * 512 + tid) * 8);

#pragma unroll
  for (int c = 0; c < 36; ++c) {
    __syncthreads();   // barrier1: all frag reads of chunk c-1 complete
    {
      _Float16 h00 = (_Float16)wv.x, h01 = (_Float16)wv.y;
      _Float16 h10 = (_Float16)wv.z, h11 = (_Float16)wv.w;
      half8 r;
#pragma unroll
      for (int e = 0; e < 8; ++e)
        r[e] = g00[e] * h00 + g01[e] * h01 + g10[e] * h10 + g11[e] * h11;
      *(half8*)&As[ar][aci] = r;
    }
#pragma unroll
    for (int q = 0; q < 4; ++q)
      *(half8*)&Bs[(q * 512 + tid) * 8] = bst[q];
    __syncthreads();   // barrier2: staged data visible

    // prefetch chunk c+1 (lands during this chunk's ds_reads + MFMAs)
    if (c < 35) {
      int cn = c + 1;
      int tn = cn >> 2;
      int cin = (cn & 3) * 64;
      if ((cn & 3) == 0) {
        ofs = *(const int4*)(smp + tn * 8);
        wv = *(const float4*)(smp + tn * 8 + 4);
      }
      int ci = cin + aci;
      g00 = *(const half8*)(xh + (size_t)ofs.x + ci);
      g01 = *(const half8*)(xh + (size_t)ofs.y + ci);
      g10 = *(const half8*)(xh + (size_t)ofs.z + ci);
      g11 = *(const half8*)(xh + (size_t)ofs.w + ci);
      const _Float16* wsrc = wtp + (size_t)cn * 16384;
#pragma unroll
      for (int q = 0; q < 4; ++q)
        bst[q] = *(const half8*)(wsrc + (size_t)(q * 512 + tid) * 8);
    }

    half8 af[2][2];
#pragma unroll
    for (int kq = 0; kq < 2; ++kq)
#pragma unroll
      for (int i = 0; i < 2; ++i)
        af[kq][i] = *(const half8*)&As[mw * 32 + i * 16 + col][kq * 32 + quad * 8];

    half8 bf[2][4];
#pragma unroll
    for (int kq = 0; kq < 2; ++kq)
#pragma unroll
      for (int j = 0; j < 4; ++j)
        bf[kq][j] = *(const half8*)&Bs[((nw * 4 + j) * 2 + kq) * 512 + lane * 8];

#pragma unroll
    for (int kq = 0; kq < 2; ++kq)
#pragma unroll
      for (int i = 0; i < 2; ++i)
#pragma unroll
        for (int j = 0; j < 4; ++j)
          acc[i][j] = __builtin_amdgcn_mfma_f32_16x16x32_f16(
              af[kq][i], bf[kq][j], acc[i][j], 0, 0, 0);
  }

  // epilogue: bias + relu; f16 activations (or fp32 for the last layer)
#pragma unroll
  for (int i = 0; i < 2; ++i)
#pragma unroll
    for (int j = 0; j < 4; ++j) {
      int n = (nw * 4 + j) * 16 + col;
#pragma unroll
      for (int r = 0; r < 4; ++r) {
        int p = p0 + mw * 32 + i * 16 + quad * 4 + r;
        float v = fmaxf(acc[i][j][r] + bj[j], 0.f);
        if (outf) outf[(size_t)p * On + n] = v;
        else outh[(size_t)p * On + n] = (_Float16)v;
      }
    }
}

// ---------------------------------------------------------------------------
extern "C" void kernel_launch(void* const* d_in, const int* in_sizes, int n_in,
                              void* d_out, int out_size, void* d_ws, size_t ws_size,
                              hipStream_t stream) {
  (void)in_sizes; (void)n_in; (void)out_size; (void)ws_size;
  const float* x = (const float*)d_in[0];

  _Float16* act0h = (_Float16*)d_ws;                     // Pn*Cn f16
  _Float16* act1h = act0h + (size_t)Pn * Cn;             // Pn*Cn f16
  float* actf32   = (float*)(act1h + (size_t)Pn * Cn);   // Pn*On f32
  float* om       = actf32 + (size_t)Pn * On;            // Pn*32
  float* sampb    = om + (size_t)Pn * 32;                // Pn*9*8
  _Float16* wbop  = (_Float16*)(sampb + (size_t)Pn * 9 * 8);  // 36*2048 f16
  _Float16* wtp   = wbop + (size_t)36 * 2048;            // 256*Kc f16 (packed)

  dim3 tb(32, 8);
  k_transpose_f2h<<<dim3(HWn / 32, Cn / 32, Bn), tb, 0, stream>>>(x, act0h, Cn, HWn);

  _Float16* cur = act0h;
  _Float16* nxt = act1h;
  for (int l = 0; l < 3; ++l) {
    const float* w_off = (const float*)d_in[1 + l * 4];
    const float* b_off = (const float*)d_in[2 + l * 4];
    const float* w     = (const float*)d_in[3 + l * 4];
    const float* b     = (const float*)d_in[4 + l * 4];

    k_wt_off_pack<<<32, 256, 0, stream>>>(w_off, wbop);
    k_wt_pack<<<256, 256, 0, stream>>>(w, wtp);
    k_off_mfma<<<Pn / 32, 256, 0, stream>>>(cur, wbop, b_off, om);
    k_coords<<<(Pn * 9) / 256, 256, 0, stream>>>(om, sampb);
    k_gemm_main<<<Pn / 64, 512, 0, stream>>>(cur, sampb, wtp, b, nxt,
                                             (l == 2) ? actf32 : nullptr);
    _Float16* tswap = cur; cur = nxt; nxt = tswap;
  }
  k_transpose<<<dim3(On / 32, HWn / 32, Bn), tb, 0, stream>>>(actf32, (float*)d_out, HWn, On);
}